// Round 1
// 961.174 us; speedup vs baseline: 1.0569x; 1.0569x over previous
//
#include <hip/hip_runtime.h>
#include <cstdint>
#include <cstddef>

#define DIM 64
#define RBF 64
#define NNODE 100000
#define NEDGE 1600000

#define ETHREADS 1024
#define EWAVES 16
#define EBLOCKS 256

#define NTHREADS 768
#define NWAVES 12
#define NBLOCKS 512

#define BUFW 136              // padded row length (bf16 elems) of per-wave scratch
#define BUFSZ (16 * BUFW)     // shorts per wave (4352 B)

// LDS byte layout, edge kernel:
//   [0, 81920)          weight B-fragments (bf16): eu_w1(49152) eu_w2(16384) pe_w1(8192) pe_w2(8192)
//   [81920, 83200)      biases f32: b1[128] b2[64] pb1[64] pb2[64]
//   [83200, ...)        per-wave scratch: EWAVES * 4352
#define E_LDS_BYTES (83200 + EWAVES * BUFSZ * 2)    // 152832  (<= 163840, 1 block/CU, 16 waves)
#define N_LDS_BYTES (16896 + NWAVES * BUFSZ * 2)    // 69120   (2 blocks/CU)

typedef __attribute__((ext_vector_type(8))) short short8;
typedef __attribute__((ext_vector_type(4))) float f32x4;

__device__ __forceinline__ short f2bf(float f) {
    union { float f; uint32_t u; } v; v.f = f;
    uint32_t r = v.u + 0x7fffu + ((v.u >> 16) & 1u);   // RNE
    return (short)(r >> 16);
}

// packed RNE f32->bf16 pair: low16 = cvt(lo), high16 = cvt(hi). Bit-identical to f2bf.
__device__ __forceinline__ uint32_t cvtpk2(float lo, float hi) {
    uint32_t r;
    asm("v_cvt_pk_bf16_f32 %0, %1, %2" : "=v"(r) : "v"(lo), "v"(hi));
    return r;
}

__device__ __forceinline__ short8 mk_afrag(float4 p0, float4 p1) {
    union { short8 s; uint32_t u[4]; } r;
    r.u[0] = cvtpk2(p0.x, p0.y);
    r.u[1] = cvtpk2(p0.z, p0.w);
    r.u[2] = cvtpk2(p1.x, p1.y);
    r.u[3] = cvtpk2(p1.z, p1.w);
    return r.s;
}

// two bf16 scratch stores (different rows) from one packed convert
__device__ __forceinline__ void store_bf2(short* a, short* b, float x, float y) {
    uint32_t w = cvtpk2(x, y);
    *a = (short)w;
    *b = (short)(w >> 16);
}

__device__ __forceinline__ float sspf(float x) {
    // softplus(x) - ln2 = ln2 * (log2(1 + 2^(x*log2e)) - 1)
    float h = __builtin_amdgcn_logf(1.0f + __builtin_amdgcn_exp2f(x * 1.44269504f));
    return 0.69314718f * (h - 1.0f);
}

// Stage W[K][NCOLS] (f32 row-major, global) into LDS as packed MFMA B-fragments.
// Fragment group g = kb*NT + nt; lane L holds W[kb*32 + (L>>4)*8 + j][nt*16 + (L&15)], j=0..7.
__device__ void stage_bfrags(const float* __restrict__ W, short* dst,
                             int KB, int NT, int NCOLS, int tid, int nthr) {
    int total = KB * NT * 64;
    for (int s = tid; s < total; s += nthr) {
        int lane = s & 63;
        int g = s >> 6;
        int nt = g % NT;
        int kb = g / NT;
        int k0 = kb * 32 + ((lane >> 4) << 3);
        int col = nt * 16 + (lane & 15);
        short8 v;
        #pragma unroll
        for (int j = 0; j < 8; j++) v[j] = f2bf(W[(k0 + j) * NCOLS + col]);
        ((short8*)dst)[s] = v;
    }
}

__global__ __launch_bounds__(ETHREADS, 4) void edge_kernel(
    const float* __restrict__ nf, const float* __restrict__ ef,
    const int* __restrict__ src, const int* __restrict__ dst,
    const float* __restrict__ eu_w1, const float* __restrict__ eu_b1,
    const float* __restrict__ eu_w2, const float* __restrict__ eu_b2,
    const float* __restrict__ pe_w1, const float* __restrict__ pe_b1,
    const float* __restrict__ pe_w2, const float* __restrict__ pe_b2,
    float* __restrict__ agg, float* __restrict__ out_edge)
{
    extern __shared__ char smem[];
    short* wB   = (short*)smem;
    float* bias = (float*)(smem + 81920);
    short* bufs = (short*)(smem + 83200);

    int tid = threadIdx.x;
    stage_bfrags(eu_w1, wB,         6, 8, 128, tid, ETHREADS);
    stage_bfrags(eu_w2, wB + 24576, 4, 4, 64,  tid, ETHREADS);
    stage_bfrags(pe_w1, wB + 32768, 2, 4, 64,  tid, ETHREADS);
    stage_bfrags(pe_w2, wB + 36864, 2, 4, 64,  tid, ETHREADS);
    for (int i = tid; i < 128; i += ETHREADS) bias[i] = eu_b1[i];
    for (int i = tid; i < 64; i += ETHREADS) {
        bias[128 + i] = eu_b2[i];
        bias[192 + i] = pe_b1[i];
        bias[256 + i] = pe_b2[i];
    }
    __syncthreads();

    const int wave = tid >> 6;
    const int lane = tid & 63;
    const int q = lane >> 4;      // quad 0..3
    const int c = lane & 15;      // col / row-in-tile
    short* buf = bufs + wave * BUFSZ;

    const short8* B1 = (const short8*)wB;
    const short8* B2 = (const short8*)(wB + 24576);
    const short8* B3 = (const short8*)(wB + 32768);
    const short8* B4 = (const short8*)(wB + 36864);

    const int numTiles = NEDGE / 16;
    const int stride = gridDim.x * EWAVES;
    const int o0 = q * 8, o1 = 32 + q * 8;

    int t = blockIdx.x * EWAVES + wave;

    // ---------------- pipeline prologue ----------------
    // current tile's indices + raw rows (src 4, dst 4, ef 4 float4s per lane)
    int cs_cur = src[t * 16 + c];
    int cd_cur = dst[t * 16 + c];
    float4 raw[12];
    {
        const float* ps = nf + (size_t)cs_cur * DIM;
        const float* pd = nf + (size_t)cd_cur * DIM;
        const float* pe = ef + (size_t)(t * 16 + c) * RBF;
        raw[0]  = *(const float4*)(ps + o0); raw[1]  = *(const float4*)(ps + o0 + 4);
        raw[2]  = *(const float4*)(ps + o1); raw[3]  = *(const float4*)(ps + o1 + 4);
        raw[4]  = *(const float4*)(pd + o0); raw[5]  = *(const float4*)(pd + o0 + 4);
        raw[6]  = *(const float4*)(pd + o1); raw[7]  = *(const float4*)(pd + o1 + 4);
        raw[8]  = *(const float4*)(pe + o0); raw[9]  = *(const float4*)(pe + o0 + 4);
        raw[10] = *(const float4*)(pe + o1); raw[11] = *(const float4*)(pe + o1 + 4);
    }
    int tn = t + stride;
    int ns = 0, nd = 0;
    if (tn < numTiles) { ns = src[tn * 16 + c]; nd = dst[tn * 16 + c]; }

    while (true) {
        const int e0 = t * 16;
        const int edst = cd_cur;   // this tile's dst index (lane c holds row c's dst)

        // ---- L1: x(192) @ eu_w1 -> h1(128); A-frags from prefetched raw regs ----
        f32x4 acc1[8];
        #pragma unroll
        for (int i = 0; i < 8; i++) acc1[i] = (f32x4){0.f, 0.f, 0.f, 0.f};
        #pragma unroll
        for (int kb = 0; kb < 6; kb++) {
            short8 a = mk_afrag(raw[2 * kb], raw[2 * kb + 1]);
            #pragma unroll
            for (int nt = 0; nt < 8; nt++)
                acc1[nt] = __builtin_amdgcn_mfma_f32_16x16x32_bf16(
                    a, B1[(kb * 8 + nt) * 64 + lane], acc1[nt], 0, 0, 0);
        }
        // ssp + bias, store bf16 h1 to scratch (C layout: row=q*4+r, col=nt*16+c)
        #pragma unroll
        for (int nt = 0; nt < 8; nt++) {
            float b = bias[nt * 16 + c];
            float v0 = sspf(acc1[nt][0] + b);
            float v1 = sspf(acc1[nt][1] + b);
            float v2 = sspf(acc1[nt][2] + b);
            float v3 = sspf(acc1[nt][3] + b);
            short* p = buf + nt * 16 + c;
            store_bf2(p + (q * 4 + 0) * BUFW, p + (q * 4 + 1) * BUFW, v0, v1);
            store_bf2(p + (q * 4 + 2) * BUFW, p + (q * 4 + 3) * BUFW, v2, v3);
        }

        // ---- software pipeline: issue next tile's rows + next-next indices ----
        if (tn < numTiles) {
            const float* ps = nf + (size_t)ns * DIM;
            const float* pd = nf + (size_t)nd * DIM;
            const float* pe = ef + (size_t)(tn * 16 + c) * RBF;
            raw[0]  = *(const float4*)(ps + o0); raw[1]  = *(const float4*)(ps + o0 + 4);
            raw[2]  = *(const float4*)(ps + o1); raw[3]  = *(const float4*)(ps + o1 + 4);
            raw[4]  = *(const float4*)(pd + o0); raw[5]  = *(const float4*)(pd + o0 + 4);
            raw[6]  = *(const float4*)(pd + o1); raw[7]  = *(const float4*)(pd + o1 + 4);
            raw[8]  = *(const float4*)(pe + o0); raw[9]  = *(const float4*)(pe + o0 + 4);
            raw[10] = *(const float4*)(pe + o1); raw[11] = *(const float4*)(pe + o1 + 4);
            cd_cur = nd;                       // becomes "current" next iteration
            int t2 = tn + stride;
            if (t2 < numTiles) { ns = src[t2 * 16 + c]; nd = dst[t2 * 16 + c]; }
        }

        // ---- L2: h1(128) @ eu_w2 -> new_edge(64) ----
        short8 a2[4];
        #pragma unroll
        for (int kb = 0; kb < 4; kb++)
            a2[kb] = *(const short8*)(buf + c * BUFW + kb * 32 + q * 8);
        f32x4 acc2[4];
        #pragma unroll
        for (int i = 0; i < 4; i++) acc2[i] = (f32x4){0.f, 0.f, 0.f, 0.f};
        #pragma unroll
        for (int kb = 0; kb < 4; kb++)
            #pragma unroll
            for (int nt = 0; nt < 4; nt++)
                acc2[nt] = __builtin_amdgcn_mfma_f32_16x16x32_bf16(
                    a2[kb], B2[(kb * 4 + nt) * 64 + lane], acc2[nt], 0, 0, 0);
        // new_edge: write f32 out, bf16 copy to scratch
        #pragma unroll
        for (int nt = 0; nt < 4; nt++) {
            float b = bias[128 + nt * 16 + c];
            float w0 = acc2[nt][0] + b;
            float w1 = acc2[nt][1] + b;
            float w2 = acc2[nt][2] + b;
            float w3 = acc2[nt][3] + b;
            out_edge[(size_t)(e0 + q * 4 + 0) * RBF + nt * 16 + c] = w0;
            out_edge[(size_t)(e0 + q * 4 + 1) * RBF + nt * 16 + c] = w1;
            out_edge[(size_t)(e0 + q * 4 + 2) * RBF + nt * 16 + c] = w2;
            out_edge[(size_t)(e0 + q * 4 + 3) * RBF + nt * 16 + c] = w3;
            short* p = buf + nt * 16 + c;
            store_bf2(p + (q * 4 + 0) * BUFW, p + (q * 4 + 1) * BUFW, w0, w1);
            store_bf2(p + (q * 4 + 2) * BUFW, p + (q * 4 + 3) * BUFW, w2, w3);
        }

        // ---- L3: new_edge @ pe_w1 -> ssp -> hemid(64) ----
        short8 a3[2];
        #pragma unroll
        for (int kb = 0; kb < 2; kb++)
            a3[kb] = *(const short8*)(buf + c * BUFW + kb * 32 + q * 8);
        f32x4 acc3[4];
        #pragma unroll
        for (int i = 0; i < 4; i++) acc3[i] = (f32x4){0.f, 0.f, 0.f, 0.f};
        #pragma unroll
        for (int kb = 0; kb < 2; kb++)
            #pragma unroll
            for (int nt = 0; nt < 4; nt++)
                acc3[nt] = __builtin_amdgcn_mfma_f32_16x16x32_bf16(
                    a3[kb], B3[(kb * 4 + nt) * 64 + lane], acc3[nt], 0, 0, 0);
        #pragma unroll
        for (int nt = 0; nt < 4; nt++) {
            float b = bias[192 + nt * 16 + c];
            float v0 = sspf(acc3[nt][0] + b);
            float v1 = sspf(acc3[nt][1] + b);
            float v2 = sspf(acc3[nt][2] + b);
            float v3 = sspf(acc3[nt][3] + b);
            short* p = buf + nt * 16 + c;
            store_bf2(p + (q * 4 + 0) * BUFW, p + (q * 4 + 1) * BUFW, v0, v1);
            store_bf2(p + (q * 4 + 2) * BUFW, p + (q * 4 + 3) * BUFW, v2, v3);
        }

        // ---- L4: hemid @ pe_w2 -> he(64), atomic scatter into agg[dst] ----
        short8 a4[2];
        #pragma unroll
        for (int kb = 0; kb < 2; kb++)
            a4[kb] = *(const short8*)(buf + c * BUFW + kb * 32 + q * 8);
        f32x4 acc4[4];
        #pragma unroll
        for (int i = 0; i < 4; i++) acc4[i] = (f32x4){0.f, 0.f, 0.f, 0.f};
        #pragma unroll
        for (int kb = 0; kb < 2; kb++)
            #pragma unroll
            for (int nt = 0; nt < 4; nt++)
                acc4[nt] = __builtin_amdgcn_mfma_f32_16x16x32_bf16(
                    a4[kb], B4[(kb * 4 + nt) * 64 + lane], acc4[nt], 0, 0, 0);
        // dst rows for this quad's 4 output rows via shuffle (lane r<16 holds dst[e0+r])
        int drow0 = __shfl(edst, q * 4 + 0, 64);
        int drow1 = __shfl(edst, q * 4 + 1, 64);
        int drow2 = __shfl(edst, q * 4 + 2, 64);
        int drow3 = __shfl(edst, q * 4 + 3, 64);
        #pragma unroll
        for (int nt = 0; nt < 4; nt++) {
            float b = bias[256 + nt * 16 + c];
            atomicAdd(&agg[(size_t)drow0 * DIM + nt * 16 + c], acc4[nt][0] + b);
            atomicAdd(&agg[(size_t)drow1 * DIM + nt * 16 + c], acc4[nt][1] + b);
            atomicAdd(&agg[(size_t)drow2 * DIM + nt * 16 + c], acc4[nt][2] + b);
            atomicAdd(&agg[(size_t)drow3 * DIM + nt * 16 + c], acc4[nt][3] + b);
        }

        if (tn >= numTiles) break;
        t = tn; tn += stride;
    }
}

__global__ __launch_bounds__(NTHREADS) void node_kernel(
    const float* __restrict__ nf,
    const float* __restrict__ pn2_w1, const float* __restrict__ pn2_b1,
    const float* __restrict__ pn2_w2, const float* __restrict__ pn2_b2,
    float* __restrict__ out_node /* holds agg on entry, final node feats on exit */)
{
    extern __shared__ char smem[];
    short* wB   = (short*)smem;
    float* bias = (float*)(smem + 16384);
    short* bufs = (short*)(smem + 16896);

    int tid = threadIdx.x;
    stage_bfrags(pn2_w1, wB,        2, 4, 64, tid, NTHREADS);
    stage_bfrags(pn2_w2, wB + 4096, 2, 4, 64, tid, NTHREADS);
    for (int i = tid; i < 64; i += NTHREADS) {
        bias[i]      = pn2_b1[i];
        bias[64 + i] = pn2_b2[i];
    }
    __syncthreads();

    const int wave = tid >> 6;
    const int lane = tid & 63;
    const int q = lane >> 4;
    const int c = lane & 15;
    short* buf = bufs + wave * BUFSZ;
    const short8* B1 = (const short8*)wB;
    const short8* B2 = (const short8*)(wB + 4096);

    const int numTiles = NNODE / 16;
    for (int t = blockIdx.x * NWAVES + wave; t < numTiles; t += gridDim.x * NWAVES) {
        const int n0 = t * 16;
        const float* prow = out_node + (size_t)(n0 + c) * DIM;  // agg row for lane's m=c

        f32x4 acc1[4];
        #pragma unroll
        for (int i = 0; i < 4; i++) acc1[i] = (f32x4){0.f, 0.f, 0.f, 0.f};
        #pragma unroll
        for (int kb = 0; kb < 2; kb++) {
            int off = kb * 32 + q * 8;
            float4 p0 = *(const float4*)(prow + off);
            float4 p1 = *(const float4*)(prow + off + 4);
            short8 a = mk_afrag(p0, p1);
            #pragma unroll
            for (int nt = 0; nt < 4; nt++)
                acc1[nt] = __builtin_amdgcn_mfma_f32_16x16x32_bf16(
                    a, B1[(kb * 4 + nt) * 64 + lane], acc1[nt], 0, 0, 0);
        }
        #pragma unroll
        for (int nt = 0; nt < 4; nt++) {
            float b = bias[nt * 16 + c];
            float v0 = sspf(acc1[nt][0] + b);
            float v1 = sspf(acc1[nt][1] + b);
            float v2 = sspf(acc1[nt][2] + b);
            float v3 = sspf(acc1[nt][3] + b);
            short* p = buf + nt * 16 + c;
            store_bf2(p + (q * 4 + 0) * BUFW, p + (q * 4 + 1) * BUFW, v0, v1);
            store_bf2(p + (q * 4 + 2) * BUFW, p + (q * 4 + 3) * BUFW, v2, v3);
        }

        short8 a2[2];
        #pragma unroll
        for (int kb = 0; kb < 2; kb++)
            a2[kb] = *(const short8*)(buf + c * BUFW + kb * 32 + q * 8);
        f32x4 acc2[4];
        #pragma unroll
        for (int i = 0; i < 4; i++) acc2[i] = (f32x4){0.f, 0.f, 0.f, 0.f};
        #pragma unroll
        for (int kb = 0; kb < 2; kb++)
            #pragma unroll
            for (int nt = 0; nt < 4; nt++)
                acc2[nt] = __builtin_amdgcn_mfma_f32_16x16x32_bf16(
                    a2[kb], B2[(kb * 4 + nt) * 64 + lane], acc2[nt], 0, 0, 0);

        #pragma unroll
        for (int nt = 0; nt < 4; nt++)
            #pragma unroll
            for (int r = 0; r < 4; r++) {
                size_t idx = (size_t)(n0 + q * 4 + r) * DIM + nt * 16 + c;
                out_node[idx] = nf[idx] + acc2[nt][r] + bias[64 + nt * 16 + c];
            }
    }
}

extern "C" void kernel_launch(void* const* d_in, const int* in_sizes, int n_in,
                              void* d_out, int out_size, void* d_ws, size_t ws_size,
                              hipStream_t stream) {
    const float* nf     = (const float*)d_in[0];
    const float* ef     = (const float*)d_in[1];
    const int*   src    = (const int*)d_in[2];
    const int*   dst    = (const int*)d_in[3];
    const float* eu_w1  = (const float*)d_in[4];
    const float* eu_b1  = (const float*)d_in[5];
    const float* eu_w2  = (const float*)d_in[6];
    const float* eu_b2  = (const float*)d_in[7];
    // d_in[8], d_in[9]: pn1_w / pn1_b — unused by the reference forward
    const float* pe_w1  = (const float*)d_in[10];
    const float* pe_b1  = (const float*)d_in[11];
    const float* pe_w2  = (const float*)d_in[12];
    const float* pe_b2  = (const float*)d_in[13];
    const float* pn2_w1 = (const float*)d_in[14];
    const float* pn2_b1 = (const float*)d_in[15];
    const float* pn2_w2 = (const float*)d_in[16];
    const float* pn2_b2 = (const float*)d_in[17];

    float* out_node = (float*)d_out;                       // [N,64] — used as agg accumulator first
    float* out_edge = out_node + (size_t)NNODE * DIM;      // [E,64]

    (void)d_ws; (void)ws_size; (void)in_sizes; (void)n_in; (void)out_size;

    (void)hipFuncSetAttribute((const void*)edge_kernel,
                              hipFuncAttributeMaxDynamicSharedMemorySize, E_LDS_BYTES);
    (void)hipFuncSetAttribute((const void*)node_kernel,
                              hipFuncAttributeMaxDynamicSharedMemorySize, N_LDS_BYTES);

    (void)hipMemsetAsync(out_node, 0, (size_t)NNODE * DIM * sizeof(float), stream);

    edge_kernel<<<EBLOCKS, ETHREADS, E_LDS_BYTES, stream>>>(
        nf, ef, src, dst, eu_w1, eu_b1, eu_w2, eu_b2,
        pe_w1, pe_b1, pe_w2, pe_b2, out_node, out_edge);

    node_kernel<<<NBLOCKS, NTHREADS, N_LDS_BYTES, stream>>>(
        nf, pn2_w1, pn2_b1, pn2_w2, pn2_b2, out_node);
}